// Round 1
// baseline (285.915 us; speedup 1.0000x reference)
//
#include <hip/hip_runtime.h>
#include <math.h>

// Problem constants (B=64, P=2, H=512, W=512)
#define HH 512
#define WW 512
#define BP 128                 // B*P pairs
#define SEG 16                 // segments per pair
#define PLANE (HH * WW)        // 262144 elems per (b,p) plane
#define SEG_ELEMS (PLANE / SEG) // 16384
#define NPART (BP * SEG)       // 2048 partial records

// ws float layout: [0,2048) sum, [2048,4096) sumx, [4096,6144) sumy,
// [6144,8192) maxval ; ints at float offset [8192,10240) maxidx. 40 KiB total.

__global__ __launch_bounds__(256) void dsnt_partial(
    const float* __restrict__ inp, const float* __restrict__ tgt,
    float* __restrict__ wsf, int* __restrict__ wsi)
{
    const int blk  = blockIdx.x;        // 0..2047
    const int pair = blk >> 4;          // (b*2+p)
    const int seg  = blk & 15;
    const int tid  = threadIdx.x;

    const size_t base = (size_t)pair * PLANE + (size_t)seg * SEG_ELEMS;
    const float4* __restrict__ ip = (const float4*)(inp + base);
    const float4* __restrict__ tp = (const float4*)(tgt + base);

    const float inv = 1.0f / 512.0f;

    float s = 0.0f, sx = 0.0f, sy = 0.0f;
    float mv = -1.0f;
    int   mi = 0;

#pragma unroll
    for (int t = 0; t < 16; ++t) {
        const int vidx = t * 256 + tid;        // float4 index within segment
        const float4 a = ip[vidx];
        const float4 bb = tp[vidx];
        const int f = seg * SEG_ELEMS + vidx * 4; // flat elem idx in plane
        // f % 4 == 0 so the 4 elems never cross a row (x0 <= 508)
        const float yw  = (float)((f >> 9) + 1) * inv;
        const float xw0 = (float)((f & 511) + 1) * inv;

        const float e0 = expf(a.x);
        const float e1 = expf(a.y);
        const float e2 = expf(a.z);
        const float e3 = expf(a.w);
        const float es = e0 + e1 + e2 + e3;
        s  += es;
        sx += es * xw0 + inv * (e1 + 2.0f * e2 + 3.0f * e3);
        sy += es * yw;

        // argmax of target (first-occurrence on ties within thread: ascending f, strict >)
        if (bb.x > mv) { mv = bb.x; mi = f; }
        if (bb.y > mv) { mv = bb.y; mi = f + 1; }
        if (bb.z > mv) { mv = bb.z; mi = f + 2; }
        if (bb.w > mv) { mv = bb.w; mi = f + 3; }
    }

    // wave (64-lane) reduction
#pragma unroll
    for (int off = 32; off > 0; off >>= 1) {
        s  += __shfl_down(s,  off, 64);
        sx += __shfl_down(sx, off, 64);
        sy += __shfl_down(sy, off, 64);
        const float ov = __shfl_down(mv, off, 64);
        const int   oi = __shfl_down(mi, off, 64);
        if (ov > mv || (ov == mv && oi < mi)) { mv = ov; mi = oi; }
    }

    __shared__ float rs[4], rsx[4], rsy[4], rmv[4];
    __shared__ int   rmi[4];
    const int lane = tid & 63, wid = tid >> 6;
    if (lane == 0) { rs[wid] = s; rsx[wid] = sx; rsy[wid] = sy; rmv[wid] = mv; rmi[wid] = mi; }
    __syncthreads();
    if (tid == 0) {
        float fs = rs[0], fsx = rsx[0], fsy = rsy[0], fmv = rmv[0];
        int fmi = rmi[0];
#pragma unroll
        for (int k = 1; k < 4; ++k) {
            fs += rs[k]; fsx += rsx[k]; fsy += rsy[k];
            if (rmv[k] > fmv || (rmv[k] == fmv && rmi[k] < fmi)) { fmv = rmv[k]; fmi = rmi[k]; }
        }
        wsf[blk]            = fs;
        wsf[NPART + blk]    = fsx;
        wsf[2 * NPART + blk] = fsy;
        wsf[3 * NPART + blk] = fmv;
        wsi[blk]            = fmi;
    }
}

__global__ __launch_bounds__(128) void dsnt_finalize(
    const float* __restrict__ wsf, const int* __restrict__ wsi,
    float* __restrict__ out)
{
    __shared__ float px[BP], py[BP], tx[BP], ty[BP];
    __shared__ float wsum[2];
    const int tid = threadIdx.x; // 0..127, one pair per thread

    {
        float s = 0.0f, sx = 0.0f, sy = 0.0f, mv = -1.0f;
        int mi = 0;
#pragma unroll
        for (int k = 0; k < SEG; ++k) {
            const int i = tid * SEG + k;   // segs in ascending index order
            s  += wsf[i];
            sx += wsf[NPART + i];
            sy += wsf[2 * NPART + i];
            const float v = wsf[3 * NPART + i];
            const int  ii = wsi[i];
            if (v > mv || (v == mv && ii < mi)) { mv = v; mi = ii; }
        }
        px[tid] = sx / s;
        py[tid] = sy / s;
        tx[tid] = (float)((mi & 511) + 1) * (1.0f / 512.0f);
        ty[tid] = (float)((mi >> 9) + 1) * (1.0f / 512.0f);
    }
    __syncthreads();

    float term = 0.0f;
    if (tid < 64) {
        const int b = tid;
        const float px0 = px[2 * b], px1 = px[2 * b + 1];
        const float py0 = py[2 * b], py1 = py[2 * b + 1];
        const float tx0 = tx[2 * b], tx1 = tx[2 * b + 1];
        const float ty0 = ty[2 * b], ty1 = ty[2 * b + 1];

        const float ed0 = sqrtf((tx0 - px0) * (tx0 - px0) + (ty0 - py0) * (ty0 - py0));
        const float ed1 = sqrtf((tx1 - px1) * (tx1 - px1) + (ty1 - py1) * (ty1 - py1));

        const float pvx = px0 - px1, pvy = py0 - py1;
        const float tvx = tx0 - tx1, tvy = ty0 - ty1;
        const float pd = sqrtf(pvx * pvx + pvy * pvy);
        const float td = sqrtf(tvx * tvx + tvy * tvy);
        const float dot = pvx * tvx + pvy * tvy;
        const float cosd = 1.0f - cosf(dot / (pd * td));
        term = ed0 + ed1 + fabsf(pd - td) + cosd;
    }

    // reduce within each wave, then across the 2 waves via LDS
#pragma unroll
    for (int off = 32; off > 0; off >>= 1)
        term += __shfl_down(term, off, 64);
    const int lane = tid & 63, wid = tid >> 6;
    if (lane == 0) wsum[wid] = term;
    __syncthreads();
    if (tid == 0) out[0] = (wsum[0] + wsum[1]) * (1.0f / 64.0f);
}

extern "C" void kernel_launch(void* const* d_in, const int* in_sizes, int n_in,
                              void* d_out, int out_size, void* d_ws, size_t ws_size,
                              hipStream_t stream)
{
    const float* inp = (const float*)d_in[0];
    const float* tgt = (const float*)d_in[1];
    float* out = (float*)d_out;
    float* wsf = (float*)d_ws;
    int*   wsi = (int*)((float*)d_ws + 4 * NPART);

    dsnt_partial<<<NPART, 256, 0, stream>>>(inp, tgt, wsf, wsi);
    dsnt_finalize<<<1, 128, 0, stream>>>(wsf, wsi, out);
}

// Round 2
// 280.011 us; speedup vs baseline: 1.0211x; 1.0211x over previous
//
#include <hip/hip_runtime.h>
#include <math.h>

// Problem constants (B=64, P=2, H=512, W=512)
#define HH 512
#define WW 512
#define BP 128                 // B*P pairs
#define SEG 16                 // segments per pair
#define PLANE (HH * WW)        // 262144 elems per (b,p) plane
#define SEG_ELEMS (PLANE / SEG) // 16384 elems = 4096 float4
#define NPART (BP * SEG)       // 2048 partial records

// ws float layout: [0,2048) sum, [2048,4096) sumx, [4096,6144) sumy,
// [6144,8192) maxval ; ints at float offset [8192,10240) maxidx. 40 KiB total.

__global__ __launch_bounds__(256) void dsnt_partial(
    const float* __restrict__ inp, const float* __restrict__ tgt,
    float* __restrict__ wsf, int* __restrict__ wsi)
{
    const int blk  = blockIdx.x;        // 0..2047
    const int pair = blk >> 4;          // (b*2+p)
    const int seg  = blk & 15;
    const int tid  = threadIdx.x;

    const size_t base = (size_t)pair * PLANE + (size_t)seg * SEG_ELEMS;
    const float4* __restrict__ ip = (const float4*)(inp + base);
    const float4* __restrict__ tp = (const float4*)(tgt + base);

    const float inv = 1.0f / 512.0f;
    const int segbase = seg * SEG_ELEMS;

    float s = 0.0f, sx = 0.0f, sy = 0.0f;
    float mv = -1.0f;
    int   mi = 0;

    // 4 outer iterations; each loads 4 float4 from input + 4 from target
    // back-to-back (8 outstanding 16B loads per wave) before computing.
    // MLP is the lever: R1 showed latency-bound at 2 loads in flight.
#pragma unroll
    for (int o = 0; o < 4; ++o) {
        float4 a[4], bb[4];
#pragma unroll
        for (int j = 0; j < 4; ++j) a[j]  = ip[o * 1024 + j * 256 + tid];
#pragma unroll
        for (int j = 0; j < 4; ++j) bb[j] = tp[o * 1024 + j * 256 + tid];

#pragma unroll
        for (int j = 0; j < 4; ++j) {
            const int vidx = o * 1024 + j * 256 + tid;
            const int f = segbase + vidx * 4;   // flat elem idx in plane, %4==0
            const float yw  = (float)((f >> 9) + 1) * inv;
            const float xw0 = (float)((f & 511) + 1) * inv;

            // __expf: x ~ N(0,1), |x| < ~6; fast-path exp is plenty accurate
            const float e0 = __expf(a[j].x);
            const float e1 = __expf(a[j].y);
            const float e2 = __expf(a[j].z);
            const float e3 = __expf(a[j].w);
            const float es = e0 + e1 + e2 + e3;
            s  += es;
            sx += es * xw0 + inv * (e1 + 2.0f * e2 + 3.0f * e3);
            sy += es * yw;

            if (bb[j].x > mv) { mv = bb[j].x; mi = f; }
            if (bb[j].y > mv) { mv = bb[j].y; mi = f + 1; }
            if (bb[j].z > mv) { mv = bb[j].z; mi = f + 2; }
            if (bb[j].w > mv) { mv = bb[j].w; mi = f + 3; }
        }
    }

    // wave (64-lane) reduction
#pragma unroll
    for (int off = 32; off > 0; off >>= 1) {
        s  += __shfl_down(s,  off, 64);
        sx += __shfl_down(sx, off, 64);
        sy += __shfl_down(sy, off, 64);
        const float ov = __shfl_down(mv, off, 64);
        const int   oi = __shfl_down(mi, off, 64);
        if (ov > mv || (ov == mv && oi < mi)) { mv = ov; mi = oi; }
    }

    __shared__ float rs[4], rsx[4], rsy[4], rmv[4];
    __shared__ int   rmi[4];
    const int lane = tid & 63, wid = tid >> 6;
    if (lane == 0) { rs[wid] = s; rsx[wid] = sx; rsy[wid] = sy; rmv[wid] = mv; rmi[wid] = mi; }
    __syncthreads();
    if (tid == 0) {
        float fs = rs[0], fsx = rsx[0], fsy = rsy[0], fmv = rmv[0];
        int fmi = rmi[0];
#pragma unroll
        for (int k = 1; k < 4; ++k) {
            fs += rs[k]; fsx += rsx[k]; fsy += rsy[k];
            if (rmv[k] > fmv || (rmv[k] == fmv && rmi[k] < fmi)) { fmv = rmv[k]; fmi = rmi[k]; }
        }
        wsf[blk]             = fs;
        wsf[NPART + blk]     = fsx;
        wsf[2 * NPART + blk] = fsy;
        wsf[3 * NPART + blk] = fmv;
        wsi[blk]             = fmi;
    }
}

__global__ __launch_bounds__(128) void dsnt_finalize(
    const float* __restrict__ wsf, const int* __restrict__ wsi,
    float* __restrict__ out)
{
    __shared__ float px[BP], py[BP], tx[BP], ty[BP];
    __shared__ float wsum[2];
    const int tid = threadIdx.x; // 0..127, one pair per thread

    {
        float s = 0.0f, sx = 0.0f, sy = 0.0f, mv = -1.0f;
        int mi = 0;
#pragma unroll
        for (int k = 0; k < SEG; ++k) {
            const int i = tid * SEG + k;   // segs in ascending index order
            s  += wsf[i];
            sx += wsf[NPART + i];
            sy += wsf[2 * NPART + i];
            const float v = wsf[3 * NPART + i];
            const int  ii = wsi[i];
            if (v > mv || (v == mv && ii < mi)) { mv = v; mi = ii; }
        }
        px[tid] = sx / s;
        py[tid] = sy / s;
        tx[tid] = (float)((mi & 511) + 1) * (1.0f / 512.0f);
        ty[tid] = (float)((mi >> 9) + 1) * (1.0f / 512.0f);
    }
    __syncthreads();

    float term = 0.0f;
    if (tid < 64) {
        const int b = tid;
        const float px0 = px[2 * b], px1 = px[2 * b + 1];
        const float py0 = py[2 * b], py1 = py[2 * b + 1];
        const float tx0 = tx[2 * b], tx1 = tx[2 * b + 1];
        const float ty0 = ty[2 * b], ty1 = ty[2 * b + 1];

        const float ed0 = sqrtf((tx0 - px0) * (tx0 - px0) + (ty0 - py0) * (ty0 - py0));
        const float ed1 = sqrtf((tx1 - px1) * (tx1 - px1) + (ty1 - py1) * (ty1 - py1));

        const float pvx = px0 - px1, pvy = py0 - py1;
        const float tvx = tx0 - tx1, tvy = ty0 - ty1;
        const float pd = sqrtf(pvx * pvx + pvy * pvy);
        const float td = sqrtf(tvx * tvx + tvy * tvy);
        const float dot = pvx * tvx + pvy * tvy;
        const float cosd = 1.0f - cosf(dot / (pd * td));
        term = ed0 + ed1 + fabsf(pd - td) + cosd;
    }

#pragma unroll
    for (int off = 32; off > 0; off >>= 1)
        term += __shfl_down(term, off, 64);
    const int lane = tid & 63, wid = tid >> 6;
    if (lane == 0) wsum[wid] = term;
    __syncthreads();
    if (tid == 0) out[0] = (wsum[0] + wsum[1]) * (1.0f / 64.0f);
}

extern "C" void kernel_launch(void* const* d_in, const int* in_sizes, int n_in,
                              void* d_out, int out_size, void* d_ws, size_t ws_size,
                              hipStream_t stream)
{
    const float* inp = (const float*)d_in[0];
    const float* tgt = (const float*)d_in[1];
    float* out = (float*)d_out;
    float* wsf = (float*)d_ws;
    int*   wsi = (int*)((float*)d_ws + 4 * NPART);

    dsnt_partial<<<NPART, 256, 0, stream>>>(inp, tgt, wsf, wsi);
    dsnt_finalize<<<1, 128, 0, stream>>>(wsf, wsi, out);
}